// Round 3
// baseline (625.596 us; speedup 1.0000x reference)
//
#include <hip/hip_runtime.h>

#define D_FEAT 64
#define BUCKET_BITS 8                 // 256 dst nodes per bucket
#define BUCKET_NODES (1 << BUCKET_BITS)
#define BIN_TILE 4096                 // edges per block in bin pass
#define SRC_BITS 17                   // n_nodes < 131072
#define SRC_MASK ((1u << SRC_BITS) - 1u)

// --- Pass 1: out-degree histogram (global int atomics) + bucket histogram (LDS-staged) ---
__global__ void k_hist(const int* __restrict__ src, const int* __restrict__ dst,
                       int* __restrict__ out_cnt, int* __restrict__ btot,
                       int n_edges, int n_buckets) {
    __shared__ int bh[1024];
    for (int i = threadIdx.x; i < n_buckets; i += blockDim.x) bh[i] = 0;
    __syncthreads();
    int i = blockIdx.x * blockDim.x + threadIdx.x;
    int stride = gridDim.x * blockDim.x;
    for (; i < n_edges; i += stride) {
        atomicAdd(&out_cnt[src[i]], 1);
        atomicAdd(&bh[dst[i] >> BUCKET_BITS], 1);
    }
    __syncthreads();
    for (int b = threadIdx.x; b < n_buckets; b += blockDim.x) {
        int v = bh[b];
        if (v) atomicAdd(&btot[b], v);
    }
}

// --- Pass 2: oscale = rsqrt(max(out_deg,1)) ---
__global__ void k_oscale(const int* __restrict__ out_cnt, float* __restrict__ oscale,
                         int n_nodes) {
    int i = blockIdx.x * blockDim.x + threadIdx.x;
    if (i < n_nodes) oscale[i] = rsqrtf((float)max(out_cnt[i], 1));
}

// --- Pass 3: exclusive scan of bucket totals (single 1024-thread block; NB <= 1024) ---
__global__ void k_scan(const int* __restrict__ btot, int* __restrict__ boff,
                       int* __restrict__ gcur, int n_buckets) {
    __shared__ int sh[1024];
    const int t = threadIdx.x;
    int v = (t < n_buckets) ? btot[t] : 0;
    sh[t] = v;
    __syncthreads();
    for (int off = 1; off < 1024; off <<= 1) {
        int x = (t >= off) ? sh[t - off] : 0;
        __syncthreads();
        sh[t] += x;
        __syncthreads();
    }
    int incl = sh[t];
    int excl = incl - v;
    if (t < n_buckets) { boff[t] = excl; gcur[t] = excl; }
    if (t == n_buckets - 1) boff[n_buckets] = incl;
}

// --- Pass 4: bin edges into bucket segments via block-local counting sort.
//     Writes packed (dst_local<<17 | src) in coalesced runs. ---
__global__ void __launch_bounds__(1024)
k_bin(const int* __restrict__ src, const int* __restrict__ dst,
      int* __restrict__ gcur, unsigned* __restrict__ sorted,
      int n_edges, int n_buckets) {
    __shared__ int bs_hist[1024];           // hist -> scan -> local cursor
    __shared__ int bs_delta[1024];          // global_base - local_start per bucket
    __shared__ unsigned bs_val[BIN_TILE];   // locally sorted packed edges
    __shared__ unsigned short bs_b[BIN_TILE];

    const int t = threadIdx.x;
    const int base = blockIdx.x * BIN_TILE;
    const int tcount = min(BIN_TILE, n_edges - base);

    bs_hist[t] = 0;
    __syncthreads();

    // load 4 edges/thread (coalesced), histogram buckets
    int es[4], ed[4];
    #pragma unroll
    for (int j = 0; j < 4; ++j) {
        int idx = t + j * 1024;
        if (idx < tcount) {
            es[j] = src[base + idx];
            ed[j] = dst[base + idx];
            atomicAdd(&bs_hist[ed[j] >> BUCKET_BITS], 1);
        } else { es[j] = -1; ed[j] = 0; }
    }
    __syncthreads();

    // in-place Hillis-Steele inclusive scan over 1024 counters
    int cnt = bs_hist[t];
    for (int off = 1; off < 1024; off <<= 1) {
        int x = (t >= off) ? bs_hist[t - off] : 0;
        __syncthreads();
        bs_hist[t] += x;
        __syncthreads();
    }
    int excl = bs_hist[t] - cnt;
    __syncthreads();                        // all reads of scanned values done
    bs_hist[t] = excl;                      // becomes local cursor
    if (cnt > 0 && t < n_buckets)
        bs_delta[t] = atomicAdd(&gcur[t], cnt) - excl;
    __syncthreads();

    // local scatter into LDS (sorted by bucket within tile)
    #pragma unroll
    for (int j = 0; j < 4; ++j) {
        if (es[j] >= 0) {
            int b = ed[j] >> BUCKET_BITS;
            int pos = atomicAdd(&bs_hist[b], 1);
            bs_val[pos] = ((unsigned)(ed[j] & (BUCKET_NODES - 1)) << SRC_BITS) | (unsigned)es[j];
            bs_b[pos] = (unsigned short)b;
        }
    }
    __syncthreads();

    // write out: consecutive i within a bucket run -> consecutive global addresses
    for (int i = t; i < tcount; i += 1024)
        sorted[i + bs_delta[bs_b[i]]] = bs_val[i];
}

// --- Pass 5: per-bucket LDS accumulation. One block per bucket; wave-per-edge,
//     lane = feature; 4-deep batched gathers for latency hiding. ---
__global__ void __launch_bounds__(1024)
k_agg(const float* __restrict__ u_f, const unsigned* __restrict__ sorted,
      const int* __restrict__ boff, const float* __restrict__ oscale,
      float* __restrict__ out, int n_nodes) {
    __shared__ float acc[BUCKET_NODES * D_FEAT];   // 64 KB
    __shared__ int cnt[BUCKET_NODES];

    const int t = threadIdx.x;
    const int b = blockIdx.x;
    const int node0 = b << BUCKET_BITS;
    const int nn = min(BUCKET_NODES, n_nodes - node0);

    for (int i = t; i < BUCKET_NODES * D_FEAT; i += 1024) acc[i] = 0.0f;
    if (t < BUCKET_NODES) cnt[t] = 0;
    __syncthreads();

    const int lo = boff[b];
    const int hi = boff[b + 1];
    const int lane = t & 63;
    const int wid = t >> 6;                        // 16 waves

    for (int c = lo + (wid << 2); c < hi; c += 64) {
        const int nj = min(4, hi - c);
        unsigned p[4]; float w[4]; float v[4]; int dl[4];
        #pragma unroll
        for (int j = 0; j < 4; ++j) if (j < nj) p[j] = sorted[c + j];
        #pragma unroll
        for (int j = 0; j < 4; ++j) if (j < nj) {
            int s = (int)(p[j] & SRC_MASK);
            dl[j] = (int)(p[j] >> SRC_BITS);
            w[j] = oscale[s];
        }
        #pragma unroll
        for (int j = 0; j < 4; ++j) if (j < nj) {
            int s = (int)(p[j] & SRC_MASK);
            v[j] = u_f[(size_t)s * D_FEAT + lane] * w[j];
        }
        #pragma unroll
        for (int j = 0; j < 4; ++j) if (j < nj) {
            atomicAdd(&acc[(dl[j] << 6) + lane], v[j]);
            if (lane == 0) atomicAdd(&cnt[dl[j]], 1);
        }
    }
    __syncthreads();

    for (int i = t; i < (nn << 6); i += 1024) {
        int nl = i >> 6;
        float s = rsqrtf((float)max(cnt[nl], 1));
        out[((size_t)(node0 + nl) << 6) + (i & 63)] = acc[i] * s;
    }
}

extern "C" void kernel_launch(void* const* d_in, const int* in_sizes, int n_in,
                              void* d_out, int out_size, void* d_ws, size_t ws_size,
                              hipStream_t stream) {
    const float* u_f = (const float*)d_in[0];
    const int*   src = (const int*)d_in[1];
    const int*   dst = (const int*)d_in[2];
    float* out = (float*)d_out;

    const int n_nodes = in_sizes[0] / D_FEAT;
    const int n_edges = in_sizes[1];
    const int n_buckets = (n_nodes + BUCKET_NODES - 1) >> BUCKET_BITS;  // 391

    // ws layout (4B units): [out_cnt n][btot NB][boff NB+1][gcur NB][oscale n][sorted m]
    int* out_cnt = (int*)d_ws;
    int* btot    = out_cnt + n_nodes;
    int* boff    = btot + n_buckets;
    int* gcur    = boff + n_buckets + 1;
    float* oscale = (float*)(gcur + n_buckets);
    unsigned* sorted = (unsigned*)(oscale + n_nodes);

    // zero out_cnt + btot (contiguous)
    hipMemsetAsync(d_ws, 0, (size_t)(n_nodes + n_buckets) * sizeof(int), stream);

    k_hist<<<512, 256, 0, stream>>>(src, dst, out_cnt, btot, n_edges, n_buckets);
    k_oscale<<<(n_nodes + 255) / 256, 256, 0, stream>>>(out_cnt, oscale, n_nodes);
    k_scan<<<1, 1024, 0, stream>>>(btot, boff, gcur, n_buckets);
    k_bin<<<(n_edges + BIN_TILE - 1) / BIN_TILE, 1024, 0, stream>>>(
        src, dst, gcur, sorted, n_edges, n_buckets);
    k_agg<<<n_buckets, 1024, 0, stream>>>(u_f, sorted, boff, oscale, out, n_nodes);
}

// Round 4
// 153.460 us; speedup vs baseline: 4.0766x; 4.0766x over previous
//
#include <hip/hip_runtime.h>

#define D_FEAT 64
#define BUCKET_BITS 8                 // 256 dst nodes per bucket
#define BUCKET_NODES (1 << BUCKET_BITS)
#define BIN_TILE 4096                 // edges per block in bin pass
#define SRC_BITS 17                   // n_nodes < 131072
#define SRC_MASK ((1u << SRC_BITS) - 1u)

// --- Pass 1: out-degree histogram (global int atomics) + bucket histogram (LDS-staged) ---
__global__ void k_hist(const int* __restrict__ src, const int* __restrict__ dst,
                       int* __restrict__ out_cnt, int* __restrict__ btot,
                       int n_edges, int n_buckets) {
    __shared__ int bh[1024];
    for (int i = threadIdx.x; i < n_buckets; i += blockDim.x) bh[i] = 0;
    __syncthreads();
    int i = blockIdx.x * blockDim.x + threadIdx.x;
    int stride = gridDim.x * blockDim.x;
    for (; i < n_edges; i += stride) {
        atomicAdd(&out_cnt[src[i]], 1);
        atomicAdd(&bh[dst[i] >> BUCKET_BITS], 1);
    }
    __syncthreads();
    for (int b = threadIdx.x; b < n_buckets; b += blockDim.x) {
        int v = bh[b];
        if (v) atomicAdd(&btot[b], v);
    }
}

// --- Pass 2: oscale = rsqrt(max(out_deg,1)) ---
__global__ void k_oscale(const int* __restrict__ out_cnt, float* __restrict__ oscale,
                         int n_nodes) {
    int i = blockIdx.x * blockDim.x + threadIdx.x;
    if (i < n_nodes) oscale[i] = rsqrtf((float)max(out_cnt[i], 1));
}

// --- Pass 3: exclusive scan of bucket totals (single 1024-thread block; NB <= 1024) ---
__global__ void k_scan(const int* __restrict__ btot, int* __restrict__ boff,
                       int* __restrict__ gcur, int* __restrict__ node_off,
                       int n_buckets, int n_nodes) {
    __shared__ int sh[1024];
    const int t = threadIdx.x;
    int v = (t < n_buckets) ? btot[t] : 0;
    sh[t] = v;
    __syncthreads();
    for (int off = 1; off < 1024; off <<= 1) {
        int x = (t >= off) ? sh[t - off] : 0;
        __syncthreads();
        sh[t] += x;
        __syncthreads();
    }
    int incl = sh[t];
    int excl = incl - v;
    if (t < n_buckets) { boff[t] = excl; gcur[t] = excl; }
    if (t == n_buckets - 1) {
        boff[n_buckets] = incl;          // = n_edges
        node_off[n_nodes] = incl;        // sentinel for cnt = diff
    }
}

// --- Pass 4: bin edges into bucket segments via block-local counting sort.
//     Writes packed (dst_local<<17 | src) in coalesced runs. ---
__global__ void __launch_bounds__(1024)
k_bin1(const int* __restrict__ src, const int* __restrict__ dst,
       int* __restrict__ gcur, unsigned* __restrict__ packed,
       int n_edges, int n_buckets) {
    __shared__ int bs_hist[1024];           // hist -> scan -> local cursor
    __shared__ int bs_delta[1024];          // global_base - local_start per bucket
    __shared__ unsigned bs_val[BIN_TILE];   // locally sorted packed edges
    __shared__ unsigned short bs_b[BIN_TILE];

    const int t = threadIdx.x;
    const int base = blockIdx.x * BIN_TILE;
    const int tcount = min(BIN_TILE, n_edges - base);

    bs_hist[t] = 0;
    __syncthreads();

    int es[4], ed[4];
    #pragma unroll
    for (int j = 0; j < 4; ++j) {
        int idx = t + j * 1024;
        if (idx < tcount) {
            es[j] = src[base + idx];
            ed[j] = dst[base + idx];
            atomicAdd(&bs_hist[ed[j] >> BUCKET_BITS], 1);
        } else { es[j] = -1; ed[j] = 0; }
    }
    __syncthreads();

    int cnt = bs_hist[t];
    for (int off = 1; off < 1024; off <<= 1) {
        int x = (t >= off) ? bs_hist[t - off] : 0;
        __syncthreads();
        bs_hist[t] += x;
        __syncthreads();
    }
    int excl = bs_hist[t] - cnt;
    __syncthreads();
    bs_hist[t] = excl;                      // becomes local cursor
    if (cnt > 0 && t < n_buckets)
        bs_delta[t] = atomicAdd(&gcur[t], cnt) - excl;
    __syncthreads();

    #pragma unroll
    for (int j = 0; j < 4; ++j) {
        if (es[j] >= 0) {
            int b = ed[j] >> BUCKET_BITS;
            int pos = atomicAdd(&bs_hist[b], 1);
            bs_val[pos] = ((unsigned)(ed[j] & (BUCKET_NODES - 1)) << SRC_BITS) | (unsigned)es[j];
            bs_b[pos] = (unsigned short)b;
        }
    }
    __syncthreads();

    for (int i = t; i < tcount; i += 1024)
        packed[i + bs_delta[bs_b[i]]] = bs_val[i];
}

// --- Pass 5: per-bucket node-order sort (light: 256 LDS counters, int atomics).
//     Emits per-node start offsets and src indices grouped by dst node. ---
__global__ void __launch_bounds__(256)
k_bin2(const unsigned* __restrict__ packed, const int* __restrict__ boff,
       int* __restrict__ node_off, int* __restrict__ sorted_src, int n_nodes) {
    __shared__ int scnt[BUCKET_NODES];
    __shared__ int scur[BUCKET_NODES];
    const int t = threadIdx.x;
    const int b = blockIdx.x;
    const int lo = boff[b], hi = boff[b + 1];

    scnt[t] = 0;
    __syncthreads();
    for (int i = lo + t; i < hi; i += 256)
        atomicAdd(&scnt[packed[i] >> SRC_BITS], 1);
    __syncthreads();

    int v = scnt[t];
    scur[t] = v;
    __syncthreads();
    for (int off = 1; off < 256; off <<= 1) {
        int x = (t >= off) ? scur[t - off] : 0;
        __syncthreads();
        scur[t] += x;
        __syncthreads();
    }
    const int excl = scur[t] - v;
    __syncthreads();
    scur[t] = lo + excl;
    const int node = (b << BUCKET_BITS) + t;
    if (node < n_nodes) node_off[node] = lo + excl;
    __syncthreads();

    for (int i = lo + t; i < hi; i += 256) {
        unsigned p = packed[i];
        int pos = atomicAdd(&scur[p >> SRC_BITS], 1);
        sorted_src[pos] = (int)(p & SRC_MASK);
    }
}

// --- Pass 6: gather-aggregate. One wave per dst node; 16 lanes x float4 per row,
//     4 edges in flight per wave instruction; shfl_xor cross-group reduce. ---
__global__ void __launch_bounds__(512)
k_agg(const float* __restrict__ u_f, const int* __restrict__ sorted_src,
      const int* __restrict__ node_off, const float* __restrict__ oscale,
      float* __restrict__ out, int n_nodes) {
    const int t = threadIdx.x;
    const int node = blockIdx.x * 8 + (t >> 6);
    if (node >= n_nodes) return;
    const int lane = t & 63;
    const int g = lane >> 4;          // edge group 0..3
    const int fq = lane & 15;         // float4 index within the 64-feat row
    const int start = node_off[node];
    const int cnt = node_off[node + 1] - start;

    float4 acc = make_float4(0.f, 0.f, 0.f, 0.f);
    for (int k = g; k < cnt; k += 4) {
        const int s = sorted_src[start + k];
        const float w = oscale[s];
        const float4 v = reinterpret_cast<const float4*>(u_f + ((size_t)s << 6))[fq];
        acc.x += v.x * w; acc.y += v.y * w; acc.z += v.z * w; acc.w += v.w * w;
    }
    #pragma unroll
    for (int off = 16; off < 64; off <<= 1) {
        acc.x += __shfl_xor(acc.x, off);
        acc.y += __shfl_xor(acc.y, off);
        acc.z += __shfl_xor(acc.z, off);
        acc.w += __shfl_xor(acc.w, off);
    }
    if (g == 0) {
        const float isc = rsqrtf((float)max(cnt, 1));
        float4 r = make_float4(acc.x * isc, acc.y * isc, acc.z * isc, acc.w * isc);
        reinterpret_cast<float4*>(out + ((size_t)node << 6))[fq] = r;
    }
}

extern "C" void kernel_launch(void* const* d_in, const int* in_sizes, int n_in,
                              void* d_out, int out_size, void* d_ws, size_t ws_size,
                              hipStream_t stream) {
    const float* u_f = (const float*)d_in[0];
    const int*   src = (const int*)d_in[1];
    const int*   dst = (const int*)d_in[2];
    float* out = (float*)d_out;

    const int n_nodes = in_sizes[0] / D_FEAT;
    const int n_edges = in_sizes[1];
    const int n_buckets = (n_nodes + BUCKET_NODES - 1) >> BUCKET_BITS;  // 391

    // ws layout (4B units):
    // [out_cnt n][btot NB] | [boff NB+1][gcur NB][oscale n][node_off n+1][packed m][sorted_src m]
    int* out_cnt  = (int*)d_ws;
    int* btot     = out_cnt + n_nodes;
    int* boff     = btot + n_buckets;
    int* gcur     = boff + n_buckets + 1;
    float* oscale = (float*)(gcur + n_buckets);
    int* node_off = (int*)(oscale + n_nodes);
    unsigned* packed = (unsigned*)(node_off + n_nodes + 1);
    int* sorted_src  = (int*)(packed + n_edges);

    // zero out_cnt + btot (contiguous)
    hipMemsetAsync(d_ws, 0, (size_t)(n_nodes + n_buckets) * sizeof(int), stream);

    k_hist<<<512, 256, 0, stream>>>(src, dst, out_cnt, btot, n_edges, n_buckets);
    k_oscale<<<(n_nodes + 255) / 256, 256, 0, stream>>>(out_cnt, oscale, n_nodes);
    k_scan<<<1, 1024, 0, stream>>>(btot, boff, gcur, node_off, n_buckets, n_nodes);
    k_bin1<<<(n_edges + BIN_TILE - 1) / BIN_TILE, 1024, 0, stream>>>(
        src, dst, gcur, packed, n_edges, n_buckets);
    k_bin2<<<n_buckets, 256, 0, stream>>>(packed, boff, node_off, sorted_src, n_nodes);

    const int agg_blocks = (n_nodes + 7) / 8;
    k_agg<<<agg_blocks, 512, 0, stream>>>(u_f, sorted_src, node_off, oscale, out, n_nodes);
}

// Round 5
// 111.656 us; speedup vs baseline: 5.6029x; 1.3744x over previous
//
#include <hip/hip_runtime.h>
#include <hip/hip_fp16.h>

#define D_FEAT 64
#define BUCKET_BITS 8                 // 256 nodes per bucket
#define BUCKET_NODES (1 << BUCKET_BITS)
#define BIN_TILE 4096                 // edges per block in bin passes
#define SRC_BITS 17                   // n_nodes < 131072
#define SRC_MASK ((1u << SRC_BITS) - 1u)
#define HIST_BLOCKS 240
#define NBP 400                       // padded bucket slots (>= n_buckets)

// --- Pass 1: per-block LDS bucket histograms (src & dst), NO global atomics ---
__global__ void k_hist(const int* __restrict__ src, const int* __restrict__ dst,
                       int* __restrict__ hist_part, int n_edges) {
    __shared__ int hs[NBP], hd[NBP];
    const int t = threadIdx.x;
    for (int i = t; i < NBP; i += 256) { hs[i] = 0; hd[i] = 0; }
    __syncthreads();
    const int4* s4 = reinterpret_cast<const int4*>(src);
    const int4* d4 = reinterpret_cast<const int4*>(dst);
    const int n4 = n_edges >> 2;
    for (int i = blockIdx.x * blockDim.x + t; i < n4; i += gridDim.x * blockDim.x) {
        int4 a = s4[i], b = d4[i];
        atomicAdd(&hs[a.x >> 8], 1); atomicAdd(&hs[a.y >> 8], 1);
        atomicAdd(&hs[a.z >> 8], 1); atomicAdd(&hs[a.w >> 8], 1);
        atomicAdd(&hd[b.x >> 8], 1); atomicAdd(&hd[b.y >> 8], 1);
        atomicAdd(&hd[b.z >> 8], 1); atomicAdd(&hd[b.w >> 8], 1);
    }
    const int rem = n_edges & 3;
    if (blockIdx.x == 0 && t < rem) {
        int e = (n_edges & ~3) + t;
        atomicAdd(&hs[src[e] >> 8], 1);
        atomicAdd(&hd[dst[e] >> 8], 1);
    }
    __syncthreads();
    int* outp = hist_part + (size_t)blockIdx.x * 2 * NBP;
    for (int i = t; i < NBP; i += 256) { outp[i] = hs[i]; outp[NBP + i] = hd[i]; }
}

// --- Pass 2: one wave per bucket sums the partials ---
__global__ void k_reduce(const int* __restrict__ hist_part, int* __restrict__ btot_s,
                         int* __restrict__ btot_d, int n_buckets) {
    const int j = (blockIdx.x * blockDim.x + threadIdx.x) >> 6;
    const int lane = threadIdx.x & 63;
    if (j >= 2 * n_buckets) return;
    const int which = (j >= n_buckets) ? 1 : 0;
    const int b = j - which * n_buckets;
    int v = 0;
    for (int i = lane; i < HIST_BLOCKS; i += 64)
        v += hist_part[((size_t)i * 2 + which) * NBP + b];
    #pragma unroll
    for (int off = 32; off; off >>= 1) v += __shfl_down(v, off);
    if (lane == 0) { if (which) btot_d[b] = v; else btot_s[b] = v; }
}

// --- Pass 3: exclusive scans of both bucket-total arrays (single block) ---
__global__ void __launch_bounds__(1024)
k_scan(const int* __restrict__ btot_s, const int* __restrict__ btot_d,
       int* __restrict__ boff_s, int* __restrict__ gcur_s,
       int* __restrict__ boff_d, int* __restrict__ gcur_d,
       int* __restrict__ node_off, int n_buckets, int n_nodes, int n_edges) {
    __shared__ int sh[1024];
    const int t = threadIdx.x;
    int v = (t < n_buckets) ? btot_s[t] : 0;
    sh[t] = v; __syncthreads();
    for (int off = 1; off < 1024; off <<= 1) {
        int x = (t >= off) ? sh[t - off] : 0; __syncthreads();
        sh[t] += x; __syncthreads();
    }
    if (t < n_buckets) { boff_s[t] = sh[t] - v; gcur_s[t] = sh[t] - v; }
    if (t == 0) boff_s[n_buckets] = n_edges;
    __syncthreads();
    int w = (t < n_buckets) ? btot_d[t] : 0;
    sh[t] = w; __syncthreads();
    for (int off = 1; off < 1024; off <<= 1) {
        int x = (t >= off) ? sh[t - off] : 0; __syncthreads();
        sh[t] += x; __syncthreads();
    }
    if (t < n_buckets) { boff_d[t] = sh[t] - w; gcur_d[t] = sh[t] - w; }
    if (t == 0) { boff_d[n_buckets] = n_edges; node_off[n_nodes] = n_edges; }
}

// --- Pass 4: bucket-sort by SRC, 1-byte payload (src&255) ---
__global__ void __launch_bounds__(1024)
k_bin1s(const int* __restrict__ src, int* __restrict__ gcur_s,
        unsigned char* __restrict__ u8, int n_edges, int n_buckets) {
    __shared__ int h[1024];
    __shared__ int delta[1024];
    __shared__ unsigned char val8[BIN_TILE];
    __shared__ unsigned short bb[BIN_TILE];
    const int t = threadIdx.x;
    const int base = blockIdx.x * BIN_TILE;
    const int tcount = min(BIN_TILE, n_edges - base);
    h[t] = 0; __syncthreads();
    int es[4];
    const int e0 = base + (t << 2);
    if (e0 + 3 < n_edges) {
        int4 a = *reinterpret_cast<const int4*>(src + e0);
        es[0] = a.x; es[1] = a.y; es[2] = a.z; es[3] = a.w;
    } else {
        #pragma unroll
        for (int j = 0; j < 4; ++j) es[j] = (e0 + j < n_edges) ? src[e0 + j] : -1;
    }
    #pragma unroll
    for (int j = 0; j < 4; ++j) if (es[j] >= 0) atomicAdd(&h[es[j] >> 8], 1);
    __syncthreads();
    int cnt = h[t];
    for (int off = 1; off < 1024; off <<= 1) {
        int x = (t >= off) ? h[t - off] : 0; __syncthreads();
        h[t] += x; __syncthreads();
    }
    int excl = h[t] - cnt;
    __syncthreads();
    h[t] = excl;
    if (cnt > 0 && t < n_buckets) delta[t] = atomicAdd(&gcur_s[t], cnt) - excl;
    __syncthreads();
    #pragma unroll
    for (int j = 0; j < 4; ++j) if (es[j] >= 0) {
        int b = es[j] >> 8;
        int pos = atomicAdd(&h[b], 1);
        val8[pos] = (unsigned char)(es[j] & 255);
        bb[pos] = (unsigned short)b;
    }
    __syncthreads();
    for (int i = t; i < tcount; i += 1024)
        u8[i + delta[bb[i]]] = val8[i];
}

// --- Pass 5: per-src-bucket local count -> oscale (no global atomics) ---
__global__ void __launch_bounds__(256)
k_cnt(const unsigned char* __restrict__ u8, const int* __restrict__ boff_s,
      float* __restrict__ oscale, int n_nodes) {
    __shared__ int scnt[BUCKET_NODES];
    const int t = threadIdx.x, b = blockIdx.x;
    const int lo = boff_s[b], hi = boff_s[b + 1];
    scnt[t] = 0; __syncthreads();
    for (int i = lo + t; i < hi; i += 256) atomicAdd(&scnt[u8[i]], 1);
    __syncthreads();
    const int node = (b << BUCKET_BITS) + t;
    if (node < n_nodes) oscale[node] = rsqrtf((float)max(scnt[t], 1));
}

// --- Pass 6: prescaled fp16 feature table nf16[s] = (half)(u_f[s] * oscale[s]) ---
__global__ void k_prescale(const float* __restrict__ u_f, const float* __restrict__ oscale,
                           unsigned short* __restrict__ nf, int n_nodes) {
    int tid = blockIdx.x * blockDim.x + threadIdx.x;
    if (tid >= n_nodes * 8) return;
    const int node = tid >> 3, o = tid & 7;
    const float w = oscale[node];
    const float4* r = reinterpret_cast<const float4*>(u_f + ((size_t)node << 6));
    float4 v0 = r[o * 2], v1 = r[o * 2 + 1];
    uint4 p;
    p.x = (unsigned)__half_as_ushort(__float2half_rn(v0.x * w)) |
          ((unsigned)__half_as_ushort(__float2half_rn(v0.y * w)) << 16);
    p.y = (unsigned)__half_as_ushort(__float2half_rn(v0.z * w)) |
          ((unsigned)__half_as_ushort(__float2half_rn(v0.w * w)) << 16);
    p.z = (unsigned)__half_as_ushort(__float2half_rn(v1.x * w)) |
          ((unsigned)__half_as_ushort(__float2half_rn(v1.y * w)) << 16);
    p.w = (unsigned)__half_as_ushort(__float2half_rn(v1.z * w)) |
          ((unsigned)__half_as_ushort(__float2half_rn(v1.w * w)) << 16);
    reinterpret_cast<uint4*>(nf + ((size_t)node << 6))[o] = p;
}

// --- Pass 7: bucket-sort by DST, packed (dst_local<<17 | src) ---
__global__ void __launch_bounds__(1024)
k_bin1d(const int* __restrict__ src, const int* __restrict__ dst,
        int* __restrict__ gcur_d, unsigned* __restrict__ packed,
        int n_edges, int n_buckets) {
    __shared__ int h[1024];
    __shared__ int delta[1024];
    __shared__ unsigned valw[BIN_TILE];
    __shared__ unsigned short bb[BIN_TILE];
    const int t = threadIdx.x;
    const int base = blockIdx.x * BIN_TILE;
    const int tcount = min(BIN_TILE, n_edges - base);
    h[t] = 0; __syncthreads();
    int es[4], ed[4];
    const int e0 = base + (t << 2);
    if (e0 + 3 < n_edges) {
        int4 a = *reinterpret_cast<const int4*>(src + e0);
        int4 b = *reinterpret_cast<const int4*>(dst + e0);
        es[0] = a.x; es[1] = a.y; es[2] = a.z; es[3] = a.w;
        ed[0] = b.x; ed[1] = b.y; ed[2] = b.z; ed[3] = b.w;
    } else {
        #pragma unroll
        for (int j = 0; j < 4; ++j) {
            if (e0 + j < n_edges) { es[j] = src[e0 + j]; ed[j] = dst[e0 + j]; }
            else { es[j] = -1; ed[j] = 0; }
        }
    }
    #pragma unroll
    for (int j = 0; j < 4; ++j) if (es[j] >= 0) atomicAdd(&h[ed[j] >> 8], 1);
    __syncthreads();
    int cnt = h[t];
    for (int off = 1; off < 1024; off <<= 1) {
        int x = (t >= off) ? h[t - off] : 0; __syncthreads();
        h[t] += x; __syncthreads();
    }
    int excl = h[t] - cnt;
    __syncthreads();
    h[t] = excl;
    if (cnt > 0 && t < n_buckets) delta[t] = atomicAdd(&gcur_d[t], cnt) - excl;
    __syncthreads();
    #pragma unroll
    for (int j = 0; j < 4; ++j) if (es[j] >= 0) {
        int b = ed[j] >> 8;
        int pos = atomicAdd(&h[b], 1);
        valw[pos] = ((unsigned)(ed[j] & (BUCKET_NODES - 1)) << SRC_BITS) | (unsigned)es[j];
        bb[pos] = (unsigned short)b;
    }
    __syncthreads();
    for (int i = t; i < tcount; i += 1024)
        packed[i + delta[bb[i]]] = valw[i];
}

// --- Pass 8: per-dst-bucket node-order sort -> node_off + sorted_src ---
__global__ void __launch_bounds__(256)
k_bin2d(const unsigned* __restrict__ packed, const int* __restrict__ boff_d,
        int* __restrict__ node_off, int* __restrict__ sorted_src, int n_nodes) {
    __shared__ int scnt[BUCKET_NODES];
    __shared__ int scur[BUCKET_NODES];
    const int t = threadIdx.x;
    const int b = blockIdx.x;
    const int lo = boff_d[b], hi = boff_d[b + 1];
    scnt[t] = 0; __syncthreads();
    for (int i = lo + t; i < hi; i += 256)
        atomicAdd(&scnt[packed[i] >> SRC_BITS], 1);
    __syncthreads();
    int v = scnt[t];
    scur[t] = v; __syncthreads();
    for (int off = 1; off < 256; off <<= 1) {
        int x = (t >= off) ? scur[t - off] : 0; __syncthreads();
        scur[t] += x; __syncthreads();
    }
    const int excl = scur[t] - v;
    __syncthreads();
    scur[t] = lo + excl;
    const int node = (b << BUCKET_BITS) + t;
    if (node < n_nodes) node_off[node] = lo + excl;
    __syncthreads();
    for (int i = lo + t; i < hi; i += 256) {
        unsigned p = packed[i];
        int pos = atomicAdd(&scur[p >> SRC_BITS], 1);
        sorted_src[pos] = (int)(p & SRC_MASK);
    }
}

__device__ inline float2 u2f2(unsigned u) {
    union { unsigned u; __half2 h; } c; c.u = u;
    return __half22float2(c.h);
}

// --- Pass 9a (primary): fp16 gather-aggregate. One wave per node; 8 edge-groups
//     of 8 lanes, each lane loads 16 B (8 halves); 8 rows in flight per wave. ---
__global__ void __launch_bounds__(512)
k_agg_f16(const unsigned short* __restrict__ nf, const int* __restrict__ sorted_src,
          const int* __restrict__ node_off, float* __restrict__ out, int n_nodes) {
    const int node = blockIdx.x * 8 + (threadIdx.x >> 6);
    if (node >= n_nodes) return;
    const int lane = threadIdx.x & 63;
    const int g = lane >> 3, o = lane & 7;
    const int start = node_off[node];
    const int cnt = node_off[node + 1] - start;
    float af[8] = {0.f, 0.f, 0.f, 0.f, 0.f, 0.f, 0.f, 0.f};
    for (int k = g; k < cnt; k += 8) {
        const int s = sorted_src[start + k];
        const uint4 q = reinterpret_cast<const uint4*>(nf + ((size_t)s << 6))[o];
        float2 f;
        f = u2f2(q.x); af[0] += f.x; af[1] += f.y;
        f = u2f2(q.y); af[2] += f.x; af[3] += f.y;
        f = u2f2(q.z); af[4] += f.x; af[5] += f.y;
        f = u2f2(q.w); af[6] += f.x; af[7] += f.y;
    }
    #pragma unroll
    for (int off = 8; off < 64; off <<= 1) {
        #pragma unroll
        for (int j = 0; j < 8; ++j) af[j] += __shfl_xor(af[j], off);
    }
    if (g == 0) {
        const float isc = rsqrtf((float)max(cnt, 1));
        float4 r0 = make_float4(af[0] * isc, af[1] * isc, af[2] * isc, af[3] * isc);
        float4 r1 = make_float4(af[4] * isc, af[5] * isc, af[6] * isc, af[7] * isc);
        float4* orow = reinterpret_cast<float4*>(out + ((size_t)node << 6));
        orow[o * 2] = r0;
        orow[o * 2 + 1] = r1;
    }
}

// --- Pass 9b (fallback, small ws): f32 gather-aggregate (R4 structure) ---
__global__ void __launch_bounds__(512)
k_agg_f32(const float* __restrict__ u_f, const int* __restrict__ sorted_src,
          const int* __restrict__ node_off, const float* __restrict__ oscale,
          float* __restrict__ out, int n_nodes) {
    const int node = blockIdx.x * 8 + (threadIdx.x >> 6);
    if (node >= n_nodes) return;
    const int lane = threadIdx.x & 63;
    const int g = lane >> 4, fq = lane & 15;
    const int start = node_off[node];
    const int cnt = node_off[node + 1] - start;
    float4 acc = make_float4(0.f, 0.f, 0.f, 0.f);
    for (int k = g; k < cnt; k += 4) {
        const int s = sorted_src[start + k];
        const float w = oscale[s];
        const float4 v = reinterpret_cast<const float4*>(u_f + ((size_t)s << 6))[fq];
        acc.x += v.x * w; acc.y += v.y * w; acc.z += v.z * w; acc.w += v.w * w;
    }
    #pragma unroll
    for (int off = 16; off < 64; off <<= 1) {
        acc.x += __shfl_xor(acc.x, off);
        acc.y += __shfl_xor(acc.y, off);
        acc.z += __shfl_xor(acc.z, off);
        acc.w += __shfl_xor(acc.w, off);
    }
    if (g == 0) {
        const float isc = rsqrtf((float)max(cnt, 1));
        float4 r = make_float4(acc.x * isc, acc.y * isc, acc.z * isc, acc.w * isc);
        reinterpret_cast<float4*>(out + ((size_t)node << 6))[fq] = r;
    }
}

extern "C" void kernel_launch(void* const* d_in, const int* in_sizes, int n_in,
                              void* d_out, int out_size, void* d_ws, size_t ws_size,
                              hipStream_t stream) {
    const float* u_f = (const float*)d_in[0];
    const int*   src = (const int*)d_in[1];
    const int*   dst = (const int*)d_in[2];
    float* out = (float*)d_out;

    const int n_nodes = in_sizes[0] / D_FEAT;
    const int n_edges = in_sizes[1];
    const int n_buckets = (n_nodes + BUCKET_NODES - 1) >> BUCKET_BITS;

    // --- workspace carve-up (word units, 16B-aligned chunks) ---
    int* w = (int*)d_ws;
    size_t off = 0;
    auto alloc = [&](size_t nwords) { int* p = w + off; off += (nwords + 3) & ~(size_t)3; return p; };
    int* btot_s   = alloc(n_buckets);
    int* btot_d   = alloc(n_buckets);
    int* boff_s   = alloc(n_buckets + 1);
    int* boff_d   = alloc(n_buckets + 1);
    int* gcur_s   = alloc(n_buckets);
    int* gcur_d   = alloc(n_buckets);
    float* oscale = (float*)alloc(n_nodes);
    int* node_off = alloc(n_nodes + 1);
    size_t hist_words = (size_t)HIST_BLOCKS * 2 * NBP;
    size_t regA_words = hist_words > (size_t)n_edges ? hist_words : (size_t)n_edges;
    int* regionA = alloc(regA_words);          // hist_part, later sorted_src
    int* regionB = alloc(n_edges);             // u8 (bytes), later packed
    unsigned short* nf16 = (unsigned short*)(w + off);
    const size_t need_f16 = (off + (size_t)n_nodes * (D_FEAT / 2)) * sizeof(int);
    const bool use_f16 = ws_size >= need_f16;

    int* hist_part  = regionA;
    int* sorted_src = regionA;
    unsigned char* u8 = (unsigned char*)regionB;
    unsigned* packed  = (unsigned*)regionB;

    const int bin_blocks = (n_edges + BIN_TILE - 1) / BIN_TILE;
    const int red_blocks = (2 * n_buckets * 64 + 255) / 256;

    k_hist<<<HIST_BLOCKS, 256, 0, stream>>>(src, dst, hist_part, n_edges);
    k_reduce<<<red_blocks, 256, 0, stream>>>(hist_part, btot_s, btot_d, n_buckets);
    k_scan<<<1, 1024, 0, stream>>>(btot_s, btot_d, boff_s, gcur_s, boff_d, gcur_d,
                                   node_off, n_buckets, n_nodes, n_edges);
    k_bin1s<<<bin_blocks, 1024, 0, stream>>>(src, gcur_s, u8, n_edges, n_buckets);
    k_cnt<<<n_buckets, 256, 0, stream>>>(u8, boff_s, oscale, n_nodes);
    if (use_f16)
        k_prescale<<<(n_nodes * 8 + 255) / 256, 256, 0, stream>>>(u_f, oscale, nf16, n_nodes);
    k_bin1d<<<bin_blocks, 1024, 0, stream>>>(src, dst, gcur_d, packed, n_edges, n_buckets);
    k_bin2d<<<n_buckets, 256, 0, stream>>>(packed, boff_d, node_off, sorted_src, n_nodes);

    const int agg_blocks = (n_nodes + 7) / 8;
    if (use_f16)
        k_agg_f16<<<agg_blocks, 512, 0, stream>>>(nf16, sorted_src, node_off, out, n_nodes);
    else
        k_agg_f32<<<agg_blocks, 512, 0, stream>>>(u_f, sorted_src, node_off, oscale, out, n_nodes);
}

// Round 6
// 97.381 us; speedup vs baseline: 6.4242x; 1.1466x over previous
//
#include <hip/hip_runtime.h>
#include <hip/hip_fp16.h>

#define D_FEAT 64
#define BUCKET_BITS 8                 // 256 nodes per bucket
#define BUCKET_NODES (1 << BUCKET_BITS)
#define BIN_TILE 4096                 // edges per block in bin pass
#define SRC_BITS 17                   // n_nodes < 131072
#define SRC_MASK ((1u << SRC_BITS) - 1u)
#define HIST_BLOCKS 240
#define NBP 400                       // padded bucket slots (>= n_buckets)

// --- Pass 1: per-block LDS bucket histograms (src & dst), NO global atomics ---
__global__ void k_hist(const int* __restrict__ src, const int* __restrict__ dst,
                       int* __restrict__ hist_part, int n_edges) {
    __shared__ int hs[NBP], hd[NBP];
    const int t = threadIdx.x;
    for (int i = t; i < NBP; i += 256) { hs[i] = 0; hd[i] = 0; }
    __syncthreads();
    const int4* s4 = reinterpret_cast<const int4*>(src);
    const int4* d4 = reinterpret_cast<const int4*>(dst);
    const int n4 = n_edges >> 2;
    for (int i = blockIdx.x * blockDim.x + t; i < n4; i += gridDim.x * blockDim.x) {
        int4 a = s4[i], b = d4[i];
        atomicAdd(&hs[a.x >> 8], 1); atomicAdd(&hs[a.y >> 8], 1);
        atomicAdd(&hs[a.z >> 8], 1); atomicAdd(&hs[a.w >> 8], 1);
        atomicAdd(&hd[b.x >> 8], 1); atomicAdd(&hd[b.y >> 8], 1);
        atomicAdd(&hd[b.z >> 8], 1); atomicAdd(&hd[b.w >> 8], 1);
    }
    const int rem = n_edges & 3;
    if (blockIdx.x == 0 && t < rem) {
        int e = (n_edges & ~3) + t;
        atomicAdd(&hs[src[e] >> 8], 1);
        atomicAdd(&hd[dst[e] >> 8], 1);
    }
    __syncthreads();
    int* outp = hist_part + (size_t)blockIdx.x * 2 * NBP;
    for (int i = t; i < NBP; i += 256) { outp[i] = hs[i]; outp[NBP + i] = hd[i]; }
}

// --- Pass 2: one wave per bucket sums the partials ---
__global__ void k_reduce(const int* __restrict__ hist_part, int* __restrict__ btot_s,
                         int* __restrict__ btot_d, int n_buckets) {
    const int j = (blockIdx.x * blockDim.x + threadIdx.x) >> 6;
    const int lane = threadIdx.x & 63;
    if (j >= 2 * n_buckets) return;
    const int which = (j >= n_buckets) ? 1 : 0;
    const int b = j - which * n_buckets;
    int v = 0;
    for (int i = lane; i < HIST_BLOCKS; i += 64)
        v += hist_part[((size_t)i * 2 + which) * NBP + b];
    #pragma unroll
    for (int off = 32; off; off >>= 1) v += __shfl_down(v, off);
    if (lane == 0) { if (which) btot_d[b] = v; else btot_s[b] = v; }
}

// --- Pass 3: exclusive scans of both bucket-total arrays (single block) ---
__global__ void __launch_bounds__(1024)
k_scan(const int* __restrict__ btot_s, const int* __restrict__ btot_d,
       int* __restrict__ boff_s, int* __restrict__ gcur_s,
       int* __restrict__ boff_d, int* __restrict__ gcur_d,
       int* __restrict__ node_off, int n_buckets, int n_nodes, int n_edges) {
    __shared__ int sh[1024];
    const int t = threadIdx.x;
    int v = (t < n_buckets) ? btot_s[t] : 0;
    sh[t] = v; __syncthreads();
    for (int off = 1; off < 1024; off <<= 1) {
        int x = (t >= off) ? sh[t - off] : 0; __syncthreads();
        sh[t] += x; __syncthreads();
    }
    if (t < n_buckets) { boff_s[t] = sh[t] - v; gcur_s[t] = sh[t] - v; }
    if (t == 0) boff_s[n_buckets] = n_edges;
    __syncthreads();
    int w = (t < n_buckets) ? btot_d[t] : 0;
    sh[t] = w; __syncthreads();
    for (int off = 1; off < 1024; off <<= 1) {
        int x = (t >= off) ? sh[t - off] : 0; __syncthreads();
        sh[t] += x; __syncthreads();
    }
    if (t < n_buckets) { boff_d[t] = sh[t] - w; gcur_d[t] = sh[t] - w; }
    if (t == 0) { boff_d[n_buckets] = n_edges; node_off[n_nodes] = n_edges; }
}

// --- Pass 4: BOTH bucket sorts in one kernel. Packed dual histogram scan
//     (src-count in low 16 bits, dst-count in high 16; tile<=4096 so no carry). ---
__global__ void __launch_bounds__(1024)
k_bin12(const int* __restrict__ src, const int* __restrict__ dst,
        int* __restrict__ gcur_s, int* __restrict__ gcur_d,
        unsigned char* __restrict__ u8, unsigned* __restrict__ packed,
        int n_edges, int n_buckets) {
    __shared__ int hs[1024], hd[1024];          // hist -> cursor
    __shared__ int delta_s[1024], delta_d[1024];
    __shared__ unsigned valw[BIN_TILE];
    __shared__ unsigned short bb_s[BIN_TILE], bb_d[BIN_TILE];
    __shared__ unsigned char val8[BIN_TILE];

    const int t = threadIdx.x;
    const int base = blockIdx.x * BIN_TILE;
    const int tcount = min(BIN_TILE, n_edges - base);
    hs[t] = 0; hd[t] = 0;
    __syncthreads();

    int es[4], ed[4];
    const int e0 = base + (t << 2);
    if (e0 + 3 < n_edges) {
        int4 a = *reinterpret_cast<const int4*>(src + e0);
        int4 b = *reinterpret_cast<const int4*>(dst + e0);
        es[0] = a.x; es[1] = a.y; es[2] = a.z; es[3] = a.w;
        ed[0] = b.x; ed[1] = b.y; ed[2] = b.z; ed[3] = b.w;
    } else {
        #pragma unroll
        for (int j = 0; j < 4; ++j) {
            if (e0 + j < n_edges) { es[j] = src[e0 + j]; ed[j] = dst[e0 + j]; }
            else { es[j] = -1; ed[j] = 0; }
        }
    }
    #pragma unroll
    for (int j = 0; j < 4; ++j) if (es[j] >= 0) {
        atomicAdd(&hs[es[j] >> 8], 1);
        atomicAdd(&hd[ed[j] >> 8], 1);
    }
    __syncthreads();

    const int cs = hs[t], cd = hd[t];
    const int p = cs | (cd << 16);              // packed dual count
    hs[t] = p;
    __syncthreads();
    for (int off = 1; off < 1024; off <<= 1) {  // single scan for both sorts
        int x = (t >= off) ? hs[t - off] : 0; __syncthreads();
        hs[t] += x; __syncthreads();
    }
    const int excl = hs[t] - p;
    const int excl_s = excl & 0xFFFF;
    const int excl_d = (excl >> 16) & 0xFFFF;
    __syncthreads();
    hs[t] = excl_s; hd[t] = excl_d;             // become local cursors
    if (t < n_buckets) {
        if (cs > 0) delta_s[t] = atomicAdd(&gcur_s[t], cs) - excl_s;
        if (cd > 0) delta_d[t] = atomicAdd(&gcur_d[t], cd) - excl_d;
    }
    __syncthreads();

    #pragma unroll
    for (int j = 0; j < 4; ++j) if (es[j] >= 0) {
        const int b1 = es[j] >> 8;
        const int p1 = atomicAdd(&hs[b1], 1);
        val8[p1] = (unsigned char)(es[j] & 255);
        bb_s[p1] = (unsigned short)b1;
        const int b2 = ed[j] >> 8;
        const int p2 = atomicAdd(&hd[b2], 1);
        valw[p2] = ((unsigned)(ed[j] & (BUCKET_NODES - 1)) << SRC_BITS) | (unsigned)es[j];
        bb_d[p2] = (unsigned short)b2;
    }
    __syncthreads();

    for (int i = t; i < tcount; i += 1024) {
        u8[i + delta_s[bb_s[i]]] = val8[i];
        packed[i + delta_d[bb_d[i]]] = valw[i];
    }
}

// --- Pass 5: per-src-bucket count -> oscale in LDS -> prescaled fp16 table
//     nf16[node][64] = (half)(u_f * oscale). One block per bucket. ---
__global__ void __launch_bounds__(256)
k_cnt_prescale(const unsigned char* __restrict__ u8, const int* __restrict__ boff_s,
               const float* __restrict__ u_f, unsigned short* __restrict__ nf,
               int n_nodes) {
    __shared__ int scnt[BUCKET_NODES];
    __shared__ float osc[BUCKET_NODES];
    const int t = threadIdx.x, b = blockIdx.x;
    const int lo = boff_s[b], hi = boff_s[b + 1];
    scnt[t] = 0; __syncthreads();
    for (int i = lo + t; i < hi; i += 256) atomicAdd(&scnt[u8[i]], 1);
    __syncthreads();
    osc[t] = rsqrtf((float)max(scnt[t], 1));
    __syncthreads();
    const int node0 = b << BUCKET_BITS;
    const int nn = min(BUCKET_NODES, n_nodes - node0);
    const float4* uf4 = reinterpret_cast<const float4*>(u_f + ((size_t)node0 << 6));
    uint2* nf2 = reinterpret_cast<uint2*>(nf + ((size_t)node0 << 6));
    for (int i = t; i < nn * 16; i += 256) {     // 16 float4 per node row
        const float w = osc[i >> 4];
        float4 v = uf4[i];
        uint2 p;
        p.x = (unsigned)__half_as_ushort(__float2half_rn(v.x * w)) |
              ((unsigned)__half_as_ushort(__float2half_rn(v.y * w)) << 16);
        p.y = (unsigned)__half_as_ushort(__float2half_rn(v.z * w)) |
              ((unsigned)__half_as_ushort(__float2half_rn(v.w * w)) << 16);
        nf2[i] = p;
    }
}

// --- Pass 6: per-dst-bucket node-order sort -> node_off + sorted_src ---
__global__ void __launch_bounds__(256)
k_bin2d(const unsigned* __restrict__ packed, const int* __restrict__ boff_d,
        int* __restrict__ node_off, int* __restrict__ sorted_src, int n_nodes) {
    __shared__ int scnt[BUCKET_NODES];
    __shared__ int scur[BUCKET_NODES];
    const int t = threadIdx.x;
    const int b = blockIdx.x;
    const int lo = boff_d[b], hi = boff_d[b + 1];
    scnt[t] = 0; __syncthreads();
    for (int i = lo + t; i < hi; i += 256)
        atomicAdd(&scnt[packed[i] >> SRC_BITS], 1);
    __syncthreads();
    int v = scnt[t];
    scur[t] = v; __syncthreads();
    for (int off = 1; off < 256; off <<= 1) {
        int x = (t >= off) ? scur[t - off] : 0; __syncthreads();
        scur[t] += x; __syncthreads();
    }
    const int excl = scur[t] - v;
    __syncthreads();
    scur[t] = lo + excl;
    const int node = (b << BUCKET_BITS) + t;
    if (node < n_nodes) node_off[node] = lo + excl;
    __syncthreads();
    for (int i = lo + t; i < hi; i += 256) {
        unsigned p = packed[i];
        int pos = atomicAdd(&scur[p >> SRC_BITS], 1);
        sorted_src[pos] = (int)(p & SRC_MASK);
    }
}

__device__ inline void acc8(float* a, uint4 q) {
    union { unsigned u; __half2 h; } c;
    float2 f;
    c.u = q.x; f = __half22float2(c.h); a[0] += f.x; a[1] += f.y;
    c.u = q.y; f = __half22float2(c.h); a[2] += f.x; a[3] += f.y;
    c.u = q.z; f = __half22float2(c.h); a[4] += f.x; a[5] += f.y;
    c.u = q.w; f = __half22float2(c.h); a[6] += f.x; a[7] += f.y;
}

// --- Pass 7: octet gather-aggregate. 8 lanes per node; lane o OWNS features
//     [8o,8o+8): no cross-lane reduce. 4-deep unroll for gather MLP.
//     Wave covers 8 nodes; block of 256 covers 32 nodes. ---
__global__ void __launch_bounds__(256)
k_agg(const unsigned short* __restrict__ nf, const int* __restrict__ sorted_src,
      const int* __restrict__ node_off, float* __restrict__ out, int n_nodes) {
    const int t = threadIdx.x;
    const int node = blockIdx.x * 32 + (t >> 3);
    if (node >= n_nodes) return;
    const int o = t & 7;
    const int start = node_off[node];
    const int cnt = node_off[node + 1] - start;
    const unsigned short* base = nf + o * 8;

    float acc[8] = {0.f, 0.f, 0.f, 0.f, 0.f, 0.f, 0.f, 0.f};
    int k = 0;
    for (; k + 4 <= cnt; k += 4) {
        const int s0 = sorted_src[start + k + 0];
        const int s1 = sorted_src[start + k + 1];
        const int s2 = sorted_src[start + k + 2];
        const int s3 = sorted_src[start + k + 3];
        const uint4 q0 = *reinterpret_cast<const uint4*>(base + ((size_t)s0 << 6));
        const uint4 q1 = *reinterpret_cast<const uint4*>(base + ((size_t)s1 << 6));
        const uint4 q2 = *reinterpret_cast<const uint4*>(base + ((size_t)s2 << 6));
        const uint4 q3 = *reinterpret_cast<const uint4*>(base + ((size_t)s3 << 6));
        acc8(acc, q0); acc8(acc, q1); acc8(acc, q2); acc8(acc, q3);
    }
    for (; k < cnt; ++k) {
        const int s = sorted_src[start + k];
        const uint4 q = *reinterpret_cast<const uint4*>(base + ((size_t)s << 6));
        acc8(acc, q);
    }
    const float isc = rsqrtf((float)max(cnt, 1));
    float4 r0 = make_float4(acc[0] * isc, acc[1] * isc, acc[2] * isc, acc[3] * isc);
    float4 r1 = make_float4(acc[4] * isc, acc[5] * isc, acc[6] * isc, acc[7] * isc);
    float4* orow = reinterpret_cast<float4*>(out + ((size_t)node << 6) + o * 8);
    orow[0] = r0;
    orow[1] = r1;
}

extern "C" void kernel_launch(void* const* d_in, const int* in_sizes, int n_in,
                              void* d_out, int out_size, void* d_ws, size_t ws_size,
                              hipStream_t stream) {
    const float* u_f = (const float*)d_in[0];
    const int*   src = (const int*)d_in[1];
    const int*   dst = (const int*)d_in[2];
    float* out = (float*)d_out;

    const int n_nodes = in_sizes[0] / D_FEAT;
    const int n_edges = in_sizes[1];
    const int n_buckets = (n_nodes + BUCKET_NODES - 1) >> BUCKET_BITS;

    // --- workspace carve-up (4B words, 16B-aligned chunks) ---
    int* w = (int*)d_ws;
    size_t off = 0;
    auto alloc = [&](size_t nwords) { int* p = w + off; off += (nwords + 3) & ~(size_t)3; return p; };
    int* btot_s   = alloc(n_buckets);
    int* btot_d   = alloc(n_buckets);
    int* boff_s   = alloc(n_buckets + 1);
    int* boff_d   = alloc(n_buckets + 1);
    int* gcur_s   = alloc(n_buckets);
    int* gcur_d   = alloc(n_buckets);
    int* node_off = alloc(n_nodes + 1);
    size_t hist_words = (size_t)HIST_BLOCKS * 2 * NBP;
    size_t regA_words = hist_words > (size_t)n_edges ? hist_words : (size_t)n_edges;
    int* regionA  = alloc(regA_words);   // hist_part -> u8 -> sorted_src (sequential lifetimes)
    unsigned* packed = (unsigned*)alloc(n_edges);
    unsigned short* nf16 = (unsigned short*)alloc((size_t)n_nodes * (D_FEAT / 2));

    int* hist_part    = regionA;
    unsigned char* u8 = (unsigned char*)regionA;
    int* sorted_src   = regionA;

    const int bin_blocks = (n_edges + BIN_TILE - 1) / BIN_TILE;
    const int red_blocks = (2 * n_buckets * 64 + 255) / 256;

    k_hist<<<HIST_BLOCKS, 256, 0, stream>>>(src, dst, hist_part, n_edges);
    k_reduce<<<red_blocks, 256, 0, stream>>>(hist_part, btot_s, btot_d, n_buckets);
    k_scan<<<1, 1024, 0, stream>>>(btot_s, btot_d, boff_s, gcur_s, boff_d, gcur_d,
                                   node_off, n_buckets, n_nodes, n_edges);
    k_bin12<<<bin_blocks, 1024, 0, stream>>>(src, dst, gcur_s, gcur_d, u8, packed,
                                             n_edges, n_buckets);
    k_cnt_prescale<<<n_buckets, 256, 0, stream>>>(u8, boff_s, u_f, nf16, n_nodes);
    k_bin2d<<<n_buckets, 256, 0, stream>>>(packed, boff_d, node_off, sorted_src, n_nodes);

    const int agg_blocks = (n_nodes + 31) / 32;
    k_agg<<<agg_blocks, 256, 0, stream>>>(nf16, sorted_src, node_off, out, n_nodes);
}

// Round 7
// 89.485 us; speedup vs baseline: 6.9911x; 1.0882x over previous
//
#include <hip/hip_runtime.h>
#include <hip/hip_fp16.h>

#define D_FEAT 64
#define BUCKET_BITS 7                 // 128 nodes per bucket -> 782 buckets
#define BUCKET_NODES (1 << BUCKET_BITS)
#define BIN_TILE 4096                 // edges per block in bin pass
#define SRC_BITS 17                   // n_nodes < 131072
#define SRC_MASK ((1u << SRC_BITS) - 1u)
#define HIST_BLOCKS 240
#define NBP 800                       // padded bucket slots (>= n_buckets)
#define CAP 4096                      // LDS edge capacity in k_bin2agg

// --- Pass 1: per-block LDS bucket histograms (src & dst), NO global atomics ---
__global__ void k_hist(const int* __restrict__ src, const int* __restrict__ dst,
                       int* __restrict__ hist_part, int n_edges) {
    __shared__ int hs[NBP], hd[NBP];
    const int t = threadIdx.x;
    for (int i = t; i < NBP; i += 256) { hs[i] = 0; hd[i] = 0; }
    __syncthreads();
    const int4* s4 = reinterpret_cast<const int4*>(src);
    const int4* d4 = reinterpret_cast<const int4*>(dst);
    const int n4 = n_edges >> 2;
    for (int i = blockIdx.x * blockDim.x + t; i < n4; i += gridDim.x * blockDim.x) {
        int4 a = s4[i], b = d4[i];
        atomicAdd(&hs[a.x >> BUCKET_BITS], 1); atomicAdd(&hs[a.y >> BUCKET_BITS], 1);
        atomicAdd(&hs[a.z >> BUCKET_BITS], 1); atomicAdd(&hs[a.w >> BUCKET_BITS], 1);
        atomicAdd(&hd[b.x >> BUCKET_BITS], 1); atomicAdd(&hd[b.y >> BUCKET_BITS], 1);
        atomicAdd(&hd[b.z >> BUCKET_BITS], 1); atomicAdd(&hd[b.w >> BUCKET_BITS], 1);
    }
    const int rem = n_edges & 3;
    if (blockIdx.x == 0 && t < rem) {
        int e = (n_edges & ~3) + t;
        atomicAdd(&hs[src[e] >> BUCKET_BITS], 1);
        atomicAdd(&hd[dst[e] >> BUCKET_BITS], 1);
    }
    __syncthreads();
    int* outp = hist_part + (size_t)blockIdx.x * 2 * NBP;
    for (int i = t; i < NBP; i += 256) { outp[i] = hs[i]; outp[NBP + i] = hd[i]; }
}

// --- Pass 2: one wave per bucket sums the partials ---
__global__ void k_reduce(const int* __restrict__ hist_part, int* __restrict__ btot_s,
                         int* __restrict__ btot_d, int n_buckets) {
    const int j = (blockIdx.x * blockDim.x + threadIdx.x) >> 6;
    const int lane = threadIdx.x & 63;
    if (j >= 2 * n_buckets) return;
    const int which = (j >= n_buckets) ? 1 : 0;
    const int b = j - which * n_buckets;
    int v = 0;
    for (int i = lane; i < HIST_BLOCKS; i += 64)
        v += hist_part[((size_t)i * 2 + which) * NBP + b];
    #pragma unroll
    for (int off = 32; off; off >>= 1) v += __shfl_down(v, off);
    if (lane == 0) { if (which) btot_d[b] = v; else btot_s[b] = v; }
}

// --- Pass 3: exclusive scans of both bucket-total arrays (single block) ---
__global__ void __launch_bounds__(1024)
k_scan(const int* __restrict__ btot_s, const int* __restrict__ btot_d,
       int* __restrict__ boff_s, int* __restrict__ gcur_s,
       int* __restrict__ boff_d, int* __restrict__ gcur_d,
       int n_buckets, int n_edges) {
    __shared__ int sh[1024];
    const int t = threadIdx.x;
    int v = (t < n_buckets) ? btot_s[t] : 0;
    sh[t] = v; __syncthreads();
    for (int off = 1; off < 1024; off <<= 1) {
        int x = (t >= off) ? sh[t - off] : 0; __syncthreads();
        sh[t] += x; __syncthreads();
    }
    if (t < n_buckets) { boff_s[t] = sh[t] - v; gcur_s[t] = sh[t] - v; }
    if (t == 0) boff_s[n_buckets] = n_edges;
    __syncthreads();
    int w = (t < n_buckets) ? btot_d[t] : 0;
    sh[t] = w; __syncthreads();
    for (int off = 1; off < 1024; off <<= 1) {
        int x = (t >= off) ? sh[t - off] : 0; __syncthreads();
        sh[t] += x; __syncthreads();
    }
    if (t < n_buckets) { boff_d[t] = sh[t] - w; gcur_d[t] = sh[t] - w; }
    if (t == 0) boff_d[n_buckets] = n_edges;
}

// --- Pass 4: BOTH bucket sorts in one kernel (packed dual 16-bit scan). ---
__global__ void __launch_bounds__(1024)
k_bin12(const int* __restrict__ src, const int* __restrict__ dst,
        int* __restrict__ gcur_s, int* __restrict__ gcur_d,
        unsigned char* __restrict__ u8, unsigned* __restrict__ packed,
        int n_edges, int n_buckets) {
    __shared__ int hs[1024], hd[1024];
    __shared__ int delta_s[1024], delta_d[1024];
    __shared__ unsigned valw[BIN_TILE];
    __shared__ unsigned short bb_s[BIN_TILE], bb_d[BIN_TILE];
    __shared__ unsigned char val8[BIN_TILE];

    const int t = threadIdx.x;
    const int base = blockIdx.x * BIN_TILE;
    const int tcount = min(BIN_TILE, n_edges - base);
    hs[t] = 0; hd[t] = 0;
    __syncthreads();

    int es[4], ed[4];
    const int e0 = base + (t << 2);
    if (e0 + 3 < n_edges) {
        int4 a = *reinterpret_cast<const int4*>(src + e0);
        int4 b = *reinterpret_cast<const int4*>(dst + e0);
        es[0] = a.x; es[1] = a.y; es[2] = a.z; es[3] = a.w;
        ed[0] = b.x; ed[1] = b.y; ed[2] = b.z; ed[3] = b.w;
    } else {
        #pragma unroll
        for (int j = 0; j < 4; ++j) {
            if (e0 + j < n_edges) { es[j] = src[e0 + j]; ed[j] = dst[e0 + j]; }
            else { es[j] = -1; ed[j] = 0; }
        }
    }
    #pragma unroll
    for (int j = 0; j < 4; ++j) if (es[j] >= 0) {
        atomicAdd(&hs[es[j] >> BUCKET_BITS], 1);
        atomicAdd(&hd[ed[j] >> BUCKET_BITS], 1);
    }
    __syncthreads();

    const int cs = hs[t], cd = hd[t];
    const int p = cs | (cd << 16);
    hs[t] = p;
    __syncthreads();
    for (int off = 1; off < 1024; off <<= 1) {
        int x = (t >= off) ? hs[t - off] : 0; __syncthreads();
        hs[t] += x; __syncthreads();
    }
    const int excl = hs[t] - p;
    const int excl_s = excl & 0xFFFF;
    const int excl_d = (excl >> 16) & 0xFFFF;
    __syncthreads();
    hs[t] = excl_s; hd[t] = excl_d;
    if (t < n_buckets) {
        if (cs > 0) delta_s[t] = atomicAdd(&gcur_s[t], cs) - excl_s;
        if (cd > 0) delta_d[t] = atomicAdd(&gcur_d[t], cd) - excl_d;
    }
    __syncthreads();

    #pragma unroll
    for (int j = 0; j < 4; ++j) if (es[j] >= 0) {
        const int b1 = es[j] >> BUCKET_BITS;
        const int p1 = atomicAdd(&hs[b1], 1);
        val8[p1] = (unsigned char)(es[j] & (BUCKET_NODES - 1));
        bb_s[p1] = (unsigned short)b1;
        const int b2 = ed[j] >> BUCKET_BITS;
        const int p2 = atomicAdd(&hd[b2], 1);
        valw[p2] = ((unsigned)(ed[j] & (BUCKET_NODES - 1)) << SRC_BITS) | (unsigned)es[j];
        bb_d[p2] = (unsigned short)b2;
    }
    __syncthreads();

    for (int i = t; i < tcount; i += 1024) {
        u8[i + delta_s[bb_s[i]]] = val8[i];
        packed[i + delta_d[bb_d[i]]] = valw[i];
    }
}

// --- Pass 5: per-src-bucket count -> oscale in LDS -> prescaled fp16 table ---
__global__ void __launch_bounds__(256)
k_cnt_prescale(const unsigned char* __restrict__ u8, const int* __restrict__ boff_s,
               const float* __restrict__ u_f, unsigned short* __restrict__ nf,
               int n_nodes) {
    __shared__ int scnt[BUCKET_NODES];
    __shared__ float osc[BUCKET_NODES];
    const int t = threadIdx.x, b = blockIdx.x;
    const int lo = boff_s[b], hi = boff_s[b + 1];
    if (t < BUCKET_NODES) scnt[t] = 0;
    __syncthreads();
    for (int i = lo + t; i < hi; i += 256) atomicAdd(&scnt[u8[i]], 1);
    __syncthreads();
    if (t < BUCKET_NODES) osc[t] = rsqrtf((float)max(scnt[t], 1));
    __syncthreads();
    const int node0 = b << BUCKET_BITS;
    const int nn = min(BUCKET_NODES, n_nodes - node0);
    const float4* uf4 = reinterpret_cast<const float4*>(u_f + ((size_t)node0 << 6));
    uint2* nf2 = reinterpret_cast<uint2*>(nf + ((size_t)node0 << 6));
    for (int i = t; i < nn * 16; i += 256) {
        const float w = osc[i >> 4];
        float4 v = uf4[i];
        uint2 p;
        p.x = (unsigned)__half_as_ushort(__float2half_rn(v.x * w)) |
              ((unsigned)__half_as_ushort(__float2half_rn(v.y * w)) << 16);
        p.y = (unsigned)__half_as_ushort(__float2half_rn(v.z * w)) |
              ((unsigned)__half_as_ushort(__float2half_rn(v.w * w)) << 16);
        nf2[i] = p;
    }
}

__device__ inline void acc8(float* a, uint4 q) {
    union { unsigned u; __half2 h; } c;
    float2 f;
    c.u = q.x; f = __half22float2(c.h); a[0] += f.x; a[1] += f.y;
    c.u = q.y; f = __half22float2(c.h); a[2] += f.x; a[3] += f.y;
    c.u = q.z; f = __half22float2(c.h); a[4] += f.x; a[5] += f.y;
    c.u = q.w; f = __half22float2(c.h); a[6] += f.x; a[7] += f.y;
}

// --- Pass 6: per-bucket node sort (in LDS) + degree-ordered register gather.
//     Block = 512 thr, one dst-bucket. 8 lanes own one node; lane o owns
//     features [8o,8o+8). 8-deep gather batches. No global sorted_src. ---
#define NGROUP 64
__global__ void __launch_bounds__(512, 8)
k_bin2agg(const unsigned* __restrict__ packed, const int* __restrict__ boff_d,
          const unsigned short* __restrict__ nf, float* __restrict__ out,
          int n_nodes) {
    __shared__ int scnt[BUCKET_NODES];
    __shared__ int sstart[BUCKET_NODES];
    __shared__ int scur[BUCKET_NODES];
    __shared__ int nperm[BUCKET_NODES];
    __shared__ int dh[64];
    __shared__ int lsrc[CAP];

    const int t = threadIdx.x;
    const int b = blockIdx.x;
    const int lo = boff_d[b], hi = boff_d[b + 1];
    const int ne = hi - lo;
    const int node0 = b << BUCKET_BITS;
    const int g = t >> 3, o = t & 7;

    if (ne <= CAP) {
        if (t < BUCKET_NODES) scnt[t] = 0;
        if (t < 64) dh[t] = 0;
        __syncthreads();
        for (int i = t; i < ne; i += 512)
            atomicAdd(&scnt[packed[lo + i] >> SRC_BITS], 1);
        __syncthreads();
        // exclusive scan of scnt (128 entries)
        if (t < BUCKET_NODES) scur[t] = scnt[t];
        __syncthreads();
        for (int off = 1; off < BUCKET_NODES; off <<= 1) {
            int x = (t < BUCKET_NODES && t >= off) ? scur[t - off] : 0;
            __syncthreads();
            if (t < BUCKET_NODES) scur[t] += x;
            __syncthreads();
        }
        if (t < BUCKET_NODES) {
            sstart[t] = scur[t] - scnt[t];
            scur[t] = scur[t] - scnt[t];               // becomes scatter cursor
            atomicAdd(&dh[min(scnt[t], 63)], 1);       // degree histogram
        }
        __syncthreads();
        if (t < 64) {                                  // wave-0 shfl scan of dh
            int v = dh[t];
            int s = v;
            #pragma unroll
            for (int off = 1; off < 64; off <<= 1) {
                int x = __shfl_up(s, off);
                if ((t & 63) >= off) s += x;
            }
            dh[t] = s - v;                             // exclusive -> cursor
        }
        __syncthreads();
        if (t < BUCKET_NODES) {
            int pos = atomicAdd(&dh[min(scnt[t], 63)], 1);
            nperm[pos] = t;                            // degree-ordered nodes
        }
        // scatter edges into LDS, node-sorted
        for (int i = t; i < ne; i += 512) {
            unsigned p = packed[lo + i];
            int pos = atomicAdd(&scur[p >> SRC_BITS], 1);
            lsrc[pos] = (int)(p & SRC_MASK);
        }
        __syncthreads();

        #pragma unroll
        for (int it = 0; it < BUCKET_NODES / NGROUP; ++it) {
            const int nl = nperm[it * NGROUP + g];
            const int node = node0 + nl;
            if (node >= n_nodes) continue;
            const int start = sstart[nl];
            const int cnt = scnt[nl];
            const unsigned short* base = nf + o * 8;
            float acc[8] = {0.f,0.f,0.f,0.f,0.f,0.f,0.f,0.f};
            int k = 0;
            for (; k + 8 <= cnt; k += 8) {
                int s0 = lsrc[start+k+0], s1 = lsrc[start+k+1];
                int s2 = lsrc[start+k+2], s3 = lsrc[start+k+3];
                int s4 = lsrc[start+k+4], s5 = lsrc[start+k+5];
                int s6 = lsrc[start+k+6], s7 = lsrc[start+k+7];
                uint4 q0 = *reinterpret_cast<const uint4*>(base + ((size_t)s0 << 6));
                uint4 q1 = *reinterpret_cast<const uint4*>(base + ((size_t)s1 << 6));
                uint4 q2 = *reinterpret_cast<const uint4*>(base + ((size_t)s2 << 6));
                uint4 q3 = *reinterpret_cast<const uint4*>(base + ((size_t)s3 << 6));
                uint4 q4 = *reinterpret_cast<const uint4*>(base + ((size_t)s4 << 6));
                uint4 q5 = *reinterpret_cast<const uint4*>(base + ((size_t)s5 << 6));
                uint4 q6 = *reinterpret_cast<const uint4*>(base + ((size_t)s6 << 6));
                uint4 q7 = *reinterpret_cast<const uint4*>(base + ((size_t)s7 << 6));
                acc8(acc, q0); acc8(acc, q1); acc8(acc, q2); acc8(acc, q3);
                acc8(acc, q4); acc8(acc, q5); acc8(acc, q6); acc8(acc, q7);
            }
            for (; k + 4 <= cnt; k += 4) {
                int s0 = lsrc[start+k+0], s1 = lsrc[start+k+1];
                int s2 = lsrc[start+k+2], s3 = lsrc[start+k+3];
                uint4 q0 = *reinterpret_cast<const uint4*>(base + ((size_t)s0 << 6));
                uint4 q1 = *reinterpret_cast<const uint4*>(base + ((size_t)s1 << 6));
                uint4 q2 = *reinterpret_cast<const uint4*>(base + ((size_t)s2 << 6));
                uint4 q3 = *reinterpret_cast<const uint4*>(base + ((size_t)s3 << 6));
                acc8(acc, q0); acc8(acc, q1); acc8(acc, q2); acc8(acc, q3);
            }
            for (; k < cnt; ++k) {
                int s = lsrc[start + k];
                uint4 q = *reinterpret_cast<const uint4*>(base + ((size_t)s << 6));
                acc8(acc, q);
            }
            const float isc = rsqrtf((float)max(cnt, 1));
            float4 r0 = make_float4(acc[0]*isc, acc[1]*isc, acc[2]*isc, acc[3]*isc);
            float4 r1 = make_float4(acc[4]*isc, acc[5]*isc, acc[6]*isc, acc[7]*isc);
            float4* orow = reinterpret_cast<float4*>(out + ((size_t)node << 6) + o * 8);
            orow[0] = r0;
            orow[1] = r1;
        }
    } else {
        // Fallback for pathological buckets (> CAP edges): scan whole segment
        // per node group. Correct for any distribution, slow only if triggered.
        for (int nl = g; nl < BUCKET_NODES; nl += NGROUP) {
            const int node = node0 + nl;
            if (node >= n_nodes) continue;
            const unsigned short* base = nf + o * 8;
            float acc[8] = {0.f,0.f,0.f,0.f,0.f,0.f,0.f,0.f};
            int cnt = 0;
            for (int i = 0; i < ne; ++i) {
                unsigned p = packed[lo + i];
                if ((int)(p >> SRC_BITS) == nl) {
                    int s = (int)(p & SRC_MASK);
                    uint4 q = *reinterpret_cast<const uint4*>(base + ((size_t)s << 6));
                    acc8(acc, q);
                    ++cnt;
                }
            }
            const float isc = rsqrtf((float)max(cnt, 1));
            float4 r0 = make_float4(acc[0]*isc, acc[1]*isc, acc[2]*isc, acc[3]*isc);
            float4 r1 = make_float4(acc[4]*isc, acc[5]*isc, acc[6]*isc, acc[7]*isc);
            float4* orow = reinterpret_cast<float4*>(out + ((size_t)node << 6) + o * 8);
            orow[0] = r0;
            orow[1] = r1;
        }
    }
}

extern "C" void kernel_launch(void* const* d_in, const int* in_sizes, int n_in,
                              void* d_out, int out_size, void* d_ws, size_t ws_size,
                              hipStream_t stream) {
    const float* u_f = (const float*)d_in[0];
    const int*   src = (const int*)d_in[1];
    const int*   dst = (const int*)d_in[2];
    float* out = (float*)d_out;

    const int n_nodes = in_sizes[0] / D_FEAT;
    const int n_edges = in_sizes[1];
    const int n_buckets = (n_nodes + BUCKET_NODES - 1) >> BUCKET_BITS;  // 782

    // --- workspace carve-up (4B words, 16B-aligned chunks) ---
    int* w = (int*)d_ws;
    size_t off = 0;
    auto alloc = [&](size_t nwords) { int* p = w + off; off += (nwords + 3) & ~(size_t)3; return p; };
    int* btot_s   = alloc(n_buckets);
    int* btot_d   = alloc(n_buckets);
    int* boff_s   = alloc(n_buckets + 1);
    int* boff_d   = alloc(n_buckets + 1);
    int* gcur_s   = alloc(n_buckets);
    int* gcur_d   = alloc(n_buckets);
    size_t hist_words = (size_t)HIST_BLOCKS * 2 * NBP;
    size_t u8_words = ((size_t)n_edges + 3) >> 2;
    size_t regA_words = hist_words > u8_words ? hist_words : u8_words;
    int* regionA  = alloc(regA_words);          // hist_part -> u8 (sequential lifetimes)
    unsigned* packed = (unsigned*)alloc(n_edges);
    unsigned short* nf16 = (unsigned short*)alloc((size_t)n_nodes * (D_FEAT / 2));

    int* hist_part    = regionA;
    unsigned char* u8 = (unsigned char*)regionA;

    const int bin_blocks = (n_edges + BIN_TILE - 1) / BIN_TILE;
    const int red_blocks = (2 * n_buckets * 64 + 255) / 256;

    k_hist<<<HIST_BLOCKS, 256, 0, stream>>>(src, dst, hist_part, n_edges);
    k_reduce<<<red_blocks, 256, 0, stream>>>(hist_part, btot_s, btot_d, n_buckets);
    k_scan<<<1, 1024, 0, stream>>>(btot_s, btot_d, boff_s, gcur_s, boff_d, gcur_d,
                                   n_buckets, n_edges);
    k_bin12<<<bin_blocks, 1024, 0, stream>>>(src, dst, gcur_s, gcur_d, u8, packed,
                                             n_edges, n_buckets);
    k_cnt_prescale<<<n_buckets, 256, 0, stream>>>(u8, boff_s, u_f, nf16, n_nodes);
    k_bin2agg<<<n_buckets, 512, 0, stream>>>(packed, boff_d, nf16, out, n_nodes);
}

// Round 8
// 78.150 us; speedup vs baseline: 8.0051x; 1.1450x over previous
//
#include <hip/hip_runtime.h>
#include <hip/hip_fp16.h>

#define D_FEAT 64
#define BUCKET_BITS 7                 // 128 nodes per bucket -> 782 buckets
#define BUCKET_NODES (1 << BUCKET_BITS)
#define HALF_NODES 64                 // nodes per agg block (bucket split in 2)
#define BIN_TILE 4096                 // edges per block in bin pass
#define SRC_BITS 17                   // n_nodes < 131072
#define SRC_MASK ((1u << SRC_BITS) - 1u)
#define HIST_BLOCKS 240
#define NBP 800                       // padded bucket slots (>= n_buckets)
#define CAP2 2048                     // LDS edge capacity per half-bucket

// --- Pass 1: per-block LDS bucket histograms (src & dst), NO global atomics ---
__global__ void k_hist(const int* __restrict__ src, const int* __restrict__ dst,
                       int* __restrict__ hist_part, int n_edges) {
    __shared__ int hs[NBP], hd[NBP];
    const int t = threadIdx.x;
    for (int i = t; i < NBP; i += 256) { hs[i] = 0; hd[i] = 0; }
    __syncthreads();
    const int4* s4 = reinterpret_cast<const int4*>(src);
    const int4* d4 = reinterpret_cast<const int4*>(dst);
    const int n4 = n_edges >> 2;
    for (int i = blockIdx.x * blockDim.x + t; i < n4; i += gridDim.x * blockDim.x) {
        int4 a = s4[i], b = d4[i];
        atomicAdd(&hs[a.x >> BUCKET_BITS], 1); atomicAdd(&hs[a.y >> BUCKET_BITS], 1);
        atomicAdd(&hs[a.z >> BUCKET_BITS], 1); atomicAdd(&hs[a.w >> BUCKET_BITS], 1);
        atomicAdd(&hd[b.x >> BUCKET_BITS], 1); atomicAdd(&hd[b.y >> BUCKET_BITS], 1);
        atomicAdd(&hd[b.z >> BUCKET_BITS], 1); atomicAdd(&hd[b.w >> BUCKET_BITS], 1);
    }
    const int rem = n_edges & 3;
    if (blockIdx.x == 0 && t < rem) {
        int e = (n_edges & ~3) + t;
        atomicAdd(&hs[src[e] >> BUCKET_BITS], 1);
        atomicAdd(&hd[dst[e] >> BUCKET_BITS], 1);
    }
    __syncthreads();
    int* outp = hist_part + (size_t)blockIdx.x * 2 * NBP;
    for (int i = t; i < NBP; i += 256) { outp[i] = hs[i]; outp[NBP + i] = hd[i]; }
}

// --- Pass 2: one wave per bucket sums the partials ---
__global__ void k_reduce(const int* __restrict__ hist_part, int* __restrict__ btot_s,
                         int* __restrict__ btot_d, int n_buckets) {
    const int j = (blockIdx.x * blockDim.x + threadIdx.x) >> 6;
    const int lane = threadIdx.x & 63;
    if (j >= 2 * n_buckets) return;
    const int which = (j >= n_buckets) ? 1 : 0;
    const int b = j - which * n_buckets;
    int v = 0;
    for (int i = lane; i < HIST_BLOCKS; i += 64)
        v += hist_part[((size_t)i * 2 + which) * NBP + b];
    #pragma unroll
    for (int off = 32; off; off >>= 1) v += __shfl_down(v, off);
    if (lane == 0) { if (which) btot_d[b] = v; else btot_s[b] = v; }
}

// --- Pass 3: exclusive scans of both bucket-total arrays (single block) ---
__global__ void __launch_bounds__(1024)
k_scan(const int* __restrict__ btot_s, const int* __restrict__ btot_d,
       int* __restrict__ boff_s, int* __restrict__ gcur_s,
       int* __restrict__ boff_d, int* __restrict__ gcur_d,
       int n_buckets, int n_edges) {
    __shared__ int sh[1024];
    const int t = threadIdx.x;
    int v = (t < n_buckets) ? btot_s[t] : 0;
    sh[t] = v; __syncthreads();
    for (int off = 1; off < 1024; off <<= 1) {
        int x = (t >= off) ? sh[t - off] : 0; __syncthreads();
        sh[t] += x; __syncthreads();
    }
    if (t < n_buckets) { boff_s[t] = sh[t] - v; gcur_s[t] = sh[t] - v; }
    if (t == 0) boff_s[n_buckets] = n_edges;
    __syncthreads();
    int w = (t < n_buckets) ? btot_d[t] : 0;
    sh[t] = w; __syncthreads();
    for (int off = 1; off < 1024; off <<= 1) {
        int x = (t >= off) ? sh[t - off] : 0; __syncthreads();
        sh[t] += x; __syncthreads();
    }
    if (t < n_buckets) { boff_d[t] = sh[t] - w; gcur_d[t] = sh[t] - w; }
    if (t == 0) boff_d[n_buckets] = n_edges;
}

// --- Pass 4: BOTH bucket sorts in one kernel (packed dual 16-bit scan). ---
__global__ void __launch_bounds__(1024)
k_bin12(const int* __restrict__ src, const int* __restrict__ dst,
        int* __restrict__ gcur_s, int* __restrict__ gcur_d,
        unsigned char* __restrict__ u8, unsigned* __restrict__ packed,
        int n_edges, int n_buckets) {
    __shared__ int hs[1024], hd[1024];
    __shared__ int delta_s[1024], delta_d[1024];
    __shared__ unsigned valw[BIN_TILE];
    __shared__ unsigned short bb_s[BIN_TILE], bb_d[BIN_TILE];
    __shared__ unsigned char val8[BIN_TILE];

    const int t = threadIdx.x;
    const int base = blockIdx.x * BIN_TILE;
    const int tcount = min(BIN_TILE, n_edges - base);
    hs[t] = 0; hd[t] = 0;
    __syncthreads();

    int es[4], ed[4];
    const int e0 = base + (t << 2);
    if (e0 + 3 < n_edges) {
        int4 a = *reinterpret_cast<const int4*>(src + e0);
        int4 b = *reinterpret_cast<const int4*>(dst + e0);
        es[0] = a.x; es[1] = a.y; es[2] = a.z; es[3] = a.w;
        ed[0] = b.x; ed[1] = b.y; ed[2] = b.z; ed[3] = b.w;
    } else {
        #pragma unroll
        for (int j = 0; j < 4; ++j) {
            if (e0 + j < n_edges) { es[j] = src[e0 + j]; ed[j] = dst[e0 + j]; }
            else { es[j] = -1; ed[j] = 0; }
        }
    }
    #pragma unroll
    for (int j = 0; j < 4; ++j) if (es[j] >= 0) {
        atomicAdd(&hs[es[j] >> BUCKET_BITS], 1);
        atomicAdd(&hd[ed[j] >> BUCKET_BITS], 1);
    }
    __syncthreads();

    const int cs = hs[t], cd = hd[t];
    const int p = cs | (cd << 16);
    hs[t] = p;
    __syncthreads();
    for (int off = 1; off < 1024; off <<= 1) {
        int x = (t >= off) ? hs[t - off] : 0; __syncthreads();
        hs[t] += x; __syncthreads();
    }
    const int excl = hs[t] - p;
    const int excl_s = excl & 0xFFFF;
    const int excl_d = (excl >> 16) & 0xFFFF;
    __syncthreads();
    hs[t] = excl_s; hd[t] = excl_d;
    if (t < n_buckets) {
        if (cs > 0) delta_s[t] = atomicAdd(&gcur_s[t], cs) - excl_s;
        if (cd > 0) delta_d[t] = atomicAdd(&gcur_d[t], cd) - excl_d;
    }
    __syncthreads();

    #pragma unroll
    for (int j = 0; j < 4; ++j) if (es[j] >= 0) {
        const int b1 = es[j] >> BUCKET_BITS;
        const int p1 = atomicAdd(&hs[b1], 1);
        val8[p1] = (unsigned char)(es[j] & (BUCKET_NODES - 1));
        bb_s[p1] = (unsigned short)b1;
        const int b2 = ed[j] >> BUCKET_BITS;
        const int p2 = atomicAdd(&hd[b2], 1);
        valw[p2] = ((unsigned)(ed[j] & (BUCKET_NODES - 1)) << SRC_BITS) | (unsigned)es[j];
        bb_d[p2] = (unsigned short)b2;
    }
    __syncthreads();

    for (int i = t; i < tcount; i += 1024) {
        u8[i + delta_s[bb_s[i]]] = val8[i];
        packed[i + delta_d[bb_d[i]]] = valw[i];
    }
}

// --- Pass 5: per-src-bucket count -> oscale in LDS -> prescaled fp16 table ---
__global__ void __launch_bounds__(256)
k_cnt_prescale(const unsigned char* __restrict__ u8, const int* __restrict__ boff_s,
               const float* __restrict__ u_f, unsigned short* __restrict__ nf,
               int n_nodes) {
    __shared__ int scnt[BUCKET_NODES];
    __shared__ float osc[BUCKET_NODES];
    const int t = threadIdx.x, b = blockIdx.x;
    const int lo = boff_s[b], hi = boff_s[b + 1];
    if (t < BUCKET_NODES) scnt[t] = 0;
    __syncthreads();
    for (int i = lo + t; i < hi; i += 256) atomicAdd(&scnt[u8[i]], 1);
    __syncthreads();
    if (t < BUCKET_NODES) osc[t] = rsqrtf((float)max(scnt[t], 1));
    __syncthreads();
    const int node0 = b << BUCKET_BITS;
    const int nn = min(BUCKET_NODES, n_nodes - node0);
    const float4* uf4 = reinterpret_cast<const float4*>(u_f + ((size_t)node0 << 6));
    uint2* nf2 = reinterpret_cast<uint2*>(nf + ((size_t)node0 << 6));
    for (int i = t; i < nn * 16; i += 256) {
        const float w = osc[i >> 4];
        float4 v = uf4[i];
        uint2 p;
        p.x = (unsigned)__half_as_ushort(__float2half_rn(v.x * w)) |
              ((unsigned)__half_as_ushort(__float2half_rn(v.y * w)) << 16);
        p.y = (unsigned)__half_as_ushort(__float2half_rn(v.z * w)) |
              ((unsigned)__half_as_ushort(__float2half_rn(v.w * w)) << 16);
        nf2[i] = p;
    }
}

__device__ inline void acc8(float* a, uint4 q) {
    union { unsigned u; __half2 h; } c;
    float2 f;
    c.u = q.x; f = __half22float2(c.h); a[0] += f.x; a[1] += f.y;
    c.u = q.y; f = __half22float2(c.h); a[2] += f.x; a[3] += f.y;
    c.u = q.z; f = __half22float2(c.h); a[4] += f.x; a[5] += f.y;
    c.u = q.w; f = __half22float2(c.h); a[6] += f.x; a[7] += f.y;
}

// --- Pass 6: half-bucket agg. 2 blocks per bucket; block scans the bucket's
//     packed segment keeping only its 64 nodes' edges, node-sorts them in LDS
//     (64-entry wave scan), degree-orders the nodes, then 8-lane/node register
//     gather with 8-deep batches. 256 thr = 4 waves -> high residency. ---
__global__ void __launch_bounds__(256)
k_agg2(const unsigned* __restrict__ packed, const int* __restrict__ boff_d,
       const unsigned short* __restrict__ nf, float* __restrict__ out,
       int n_nodes) {
    __shared__ int scnt[HALF_NODES];
    __shared__ int sstart[HALF_NODES];
    __shared__ int scur[HALF_NODES];
    __shared__ int nperm[HALF_NODES];
    __shared__ int dh[64];
    __shared__ int stot;
    __shared__ int lsrc[CAP2];

    const int t = threadIdx.x;
    const int b = blockIdx.x >> 1;
    const int h = blockIdx.x & 1;
    const int lo = boff_d[b], hi = boff_d[b + 1];
    const int ne = hi - lo;
    const int nodeBase = (b << BUCKET_BITS) + h * HALF_NODES;
    const int g2 = t >> 3, o = t & 7;

    if (t < HALF_NODES) scnt[t] = 0;
    if (t < 64) dh[t] = 0;
    __syncthreads();

    // count our half's edges per node
    for (int i = t; i < ne; i += 256) {
        const unsigned p = packed[lo + i];
        const int dl = (int)(p >> SRC_BITS);
        if ((dl >> 6) == h) atomicAdd(&scnt[dl & 63], 1);
    }
    __syncthreads();

    // wave 0: exclusive scan of 64 counts + degree histogram
    if (t < 64) {
        const int v = scnt[t];
        atomicAdd(&dh[min(v, 63)], 1);
        int s = v;
        #pragma unroll
        for (int off = 1; off < 64; off <<= 1) {
            int x = __shfl_up(s, off);
            if (t >= off) s += x;
        }
        sstart[t] = s - v;
        scur[t] = s - v;
        if (t == 63) stot = s;
    }
    __syncthreads();
    // wave 0: exclusive scan of degree histogram -> cursors
    if (t < 64) {
        const int v = dh[t];
        int s = v;
        #pragma unroll
        for (int off = 1; off < 64; off <<= 1) {
            int x = __shfl_up(s, off);
            if (t >= off) s += x;
        }
        dh[t] = s - v;
    }
    __syncthreads();
    if (t < HALF_NODES) {
        const int pos = atomicAdd(&dh[min(scnt[t], 63)], 1);
        nperm[pos] = t;                 // degree-ordered local nodes
    }
    __syncthreads();

    if (stot <= CAP2) {
        // scatter our half's edges into LDS, grouped by node
        for (int i = t; i < ne; i += 256) {
            const unsigned p = packed[lo + i];
            const int dl = (int)(p >> SRC_BITS);
            if ((dl >> 6) == h) {
                const int pos = atomicAdd(&scur[dl & 63], 1);
                lsrc[pos] = (int)(p & SRC_MASK);
            }
        }
        __syncthreads();

        #pragma unroll
        for (int it = 0; it < HALF_NODES / 32; ++it) {
            const int nl = nperm[it * 32 + g2];
            const int node = nodeBase + nl;
            if (node >= n_nodes) continue;
            const int start = sstart[nl];
            const int cnt = scnt[nl];
            const unsigned short* base = nf + o * 8;
            float acc[8] = {0.f,0.f,0.f,0.f,0.f,0.f,0.f,0.f};
            int k = 0;
            for (; k + 8 <= cnt; k += 8) {
                int s0 = lsrc[start+k+0], s1 = lsrc[start+k+1];
                int s2 = lsrc[start+k+2], s3 = lsrc[start+k+3];
                int s4 = lsrc[start+k+4], s5 = lsrc[start+k+5];
                int s6 = lsrc[start+k+6], s7 = lsrc[start+k+7];
                uint4 q0 = *reinterpret_cast<const uint4*>(base + ((size_t)s0 << 6));
                uint4 q1 = *reinterpret_cast<const uint4*>(base + ((size_t)s1 << 6));
                uint4 q2 = *reinterpret_cast<const uint4*>(base + ((size_t)s2 << 6));
                uint4 q3 = *reinterpret_cast<const uint4*>(base + ((size_t)s3 << 6));
                uint4 q4 = *reinterpret_cast<const uint4*>(base + ((size_t)s4 << 6));
                uint4 q5 = *reinterpret_cast<const uint4*>(base + ((size_t)s5 << 6));
                uint4 q6 = *reinterpret_cast<const uint4*>(base + ((size_t)s6 << 6));
                uint4 q7 = *reinterpret_cast<const uint4*>(base + ((size_t)s7 << 6));
                acc8(acc, q0); acc8(acc, q1); acc8(acc, q2); acc8(acc, q3);
                acc8(acc, q4); acc8(acc, q5); acc8(acc, q6); acc8(acc, q7);
            }
            for (; k + 4 <= cnt; k += 4) {
                int s0 = lsrc[start+k+0], s1 = lsrc[start+k+1];
                int s2 = lsrc[start+k+2], s3 = lsrc[start+k+3];
                uint4 q0 = *reinterpret_cast<const uint4*>(base + ((size_t)s0 << 6));
                uint4 q1 = *reinterpret_cast<const uint4*>(base + ((size_t)s1 << 6));
                uint4 q2 = *reinterpret_cast<const uint4*>(base + ((size_t)s2 << 6));
                uint4 q3 = *reinterpret_cast<const uint4*>(base + ((size_t)s3 << 6));
                acc8(acc, q0); acc8(acc, q1); acc8(acc, q2); acc8(acc, q3);
            }
            for (; k < cnt; ++k) {
                int s = lsrc[start + k];
                uint4 q = *reinterpret_cast<const uint4*>(base + ((size_t)s << 6));
                acc8(acc, q);
            }
            const float isc = rsqrtf((float)max(cnt, 1));
            float4 r0 = make_float4(acc[0]*isc, acc[1]*isc, acc[2]*isc, acc[3]*isc);
            float4 r1 = make_float4(acc[4]*isc, acc[5]*isc, acc[6]*isc, acc[7]*isc);
            float4* orow = reinterpret_cast<float4*>(out + ((size_t)node << 6) + o * 8);
            orow[0] = r0;
            orow[1] = r1;
        }
    } else {
        // Fallback (half-bucket > CAP2 edges): direct scan per node group.
        for (int it = 0; it < HALF_NODES / 32; ++it) {
            const int nl = it * 32 + g2;
            const int node = nodeBase + nl;
            if (node >= n_nodes) continue;
            const unsigned short* base = nf + o * 8;
            float acc[8] = {0.f,0.f,0.f,0.f,0.f,0.f,0.f,0.f};
            int cnt = 0;
            for (int i = 0; i < ne; ++i) {
                const unsigned p = packed[lo + i];
                if ((int)(p >> SRC_BITS) == (h << 6) + nl) {
                    const int s = (int)(p & SRC_MASK);
                    uint4 q = *reinterpret_cast<const uint4*>(base + ((size_t)s << 6));
                    acc8(acc, q);
                    ++cnt;
                }
            }
            const float isc = rsqrtf((float)max(cnt, 1));
            float4 r0 = make_float4(acc[0]*isc, acc[1]*isc, acc[2]*isc, acc[3]*isc);
            float4 r1 = make_float4(acc[4]*isc, acc[5]*isc, acc[6]*isc, acc[7]*isc);
            float4* orow = reinterpret_cast<float4*>(out + ((size_t)node << 6) + o * 8);
            orow[0] = r0;
            orow[1] = r1;
        }
    }
}

extern "C" void kernel_launch(void* const* d_in, const int* in_sizes, int n_in,
                              void* d_out, int out_size, void* d_ws, size_t ws_size,
                              hipStream_t stream) {
    const float* u_f = (const float*)d_in[0];
    const int*   src = (const int*)d_in[1];
    const int*   dst = (const int*)d_in[2];
    float* out = (float*)d_out;

    const int n_nodes = in_sizes[0] / D_FEAT;
    const int n_edges = in_sizes[1];
    const int n_buckets = (n_nodes + BUCKET_NODES - 1) >> BUCKET_BITS;  // 782

    // --- workspace carve-up (4B words, 16B-aligned chunks) ---
    int* w = (int*)d_ws;
    size_t off = 0;
    auto alloc = [&](size_t nwords) { int* p = w + off; off += (nwords + 3) & ~(size_t)3; return p; };
    int* btot_s   = alloc(n_buckets);
    int* btot_d   = alloc(n_buckets);
    int* boff_s   = alloc(n_buckets + 1);
    int* boff_d   = alloc(n_buckets + 1);
    int* gcur_s   = alloc(n_buckets);
    int* gcur_d   = alloc(n_buckets);
    size_t hist_words = (size_t)HIST_BLOCKS * 2 * NBP;
    size_t u8_words = ((size_t)n_edges + 3) >> 2;
    size_t regA_words = hist_words > u8_words ? hist_words : u8_words;
    int* regionA  = alloc(regA_words);          // hist_part -> u8 (sequential lifetimes)
    unsigned* packed = (unsigned*)alloc(n_edges);
    unsigned short* nf16 = (unsigned short*)alloc((size_t)n_nodes * (D_FEAT / 2));

    int* hist_part    = regionA;
    unsigned char* u8 = (unsigned char*)regionA;

    const int bin_blocks = (n_edges + BIN_TILE - 1) / BIN_TILE;
    const int red_blocks = (2 * n_buckets * 64 + 255) / 256;

    k_hist<<<HIST_BLOCKS, 256, 0, stream>>>(src, dst, hist_part, n_edges);
    k_reduce<<<red_blocks, 256, 0, stream>>>(hist_part, btot_s, btot_d, n_buckets);
    k_scan<<<1, 1024, 0, stream>>>(btot_s, btot_d, boff_s, gcur_s, boff_d, gcur_d,
                                   n_buckets, n_edges);
    k_bin12<<<bin_blocks, 1024, 0, stream>>>(src, dst, gcur_s, gcur_d, u8, packed,
                                             n_edges, n_buckets);
    k_cnt_prescale<<<n_buckets, 256, 0, stream>>>(u8, boff_s, u_f, nf16, n_nodes);
    k_agg2<<<n_buckets * 2, 256, 0, stream>>>(packed, boff_d, nf16, out, n_nodes);
}